// Round 1
// baseline (1672.914 us; speedup 1.0000x reference)
//
#include <hip/hip_runtime.h>

#define N_NODES 100000
#define N_EDGES 3200000
#define F_IN    128
#define HC      32      // H*C
#define CH      16      // C per head
#define NGRAPH  64
#define NEG     0.2f

__device__ __forceinline__ float lrelu(float x) { return x > 0.f ? x : NEG * x; }

// ---------- reductions / small precompute ----------

__global__ void k_ea_sum(const float* __restrict__ ea, float* __restrict__ params) {
    float acc = 0.f;
    for (int i = blockIdx.x * blockDim.x + threadIdx.x; i < N_EDGES;
         i += gridDim.x * blockDim.x)
        acc += ea[i];
    for (int m = 32; m >= 1; m >>= 1) acc += __shfl_xor(acc, m, 64);
    __shared__ float sh[4];
    int lane = threadIdx.x & 63, wid = threadIdx.x >> 6;
    if (lane == 0) sh[wid] = acc;
    __syncthreads();
    if (threadIdx.x == 0) {
        float t = 0.f;
        for (int i = 0; i < 4; ++i) t += sh[i];
        unsafeAtomicAdd(params, t);
    }
}

// params: [0]=ea_sum, [1]=ea_mean, [2..3]=ce layer1, [4..5]=ce layer2
__global__ void k_prep(const float* __restrict__ We1, const float* __restrict__ ae1,
                       const float* __restrict__ We2, const float* __restrict__ ae2,
                       float* __restrict__ params) {
    int t = threadIdx.x;
    if (t < 2) {
        float c1 = 0.f, c2 = 0.f;
        for (int c = 0; c < CH; ++c) {
            c1 += We1[t * CH + c] * ae1[t * CH + c];
            c2 += We2[t * CH + c] * ae2[t * CH + c];
        }
        params[2 + t] = c1;
        params[4 + t] = c2;
        if (t == 0) params[1] = params[0] / (float)N_EDGES;
    }
}

// ---------- dense: h = x @ W, plus fused asrc/adst ----------

template <int FIN>
__global__ void k_linear(const float* __restrict__ x, const float* __restrict__ W,
                         const float* __restrict__ a_src, const float* __restrict__ a_dst,
                         float* __restrict__ h, float* __restrict__ asrc,
                         float* __restrict__ adst) {
    int tid = blockIdx.x * blockDim.x + threadIdx.x;
    int n = tid >> 5;
    if (n >= N_NODES) return;
    int c = tid & 31;
    const float* xr = x + (size_t)n * FIN;
    float acc = 0.f;
#pragma unroll 8
    for (int k = 0; k < FIN; ++k) acc = fmaf(xr[k], W[k * HC + c], acc);
    h[(size_t)n * HC + c] = acc;
    int hh = c >> 4, cc = c & 15;
    float vs = acc * a_src[hh * CH + cc];
    float vd = acc * a_dst[hh * CH + cc];
    for (int m = 8; m >= 1; m >>= 1) {
        vs += __shfl_xor(vs, m, 16);
        vd += __shfl_xor(vd, m, 16);
    }
    if (cc == 0) {
        asrc[n * 2 + hh] = vs;
        adst[n * 2 + hh] = vd;
    }
}

// ---------- softmax denominator: self-loop init + edge atomics ----------

__global__ void k_self_init(const float* __restrict__ asrc, const float* __restrict__ adst,
                            const float* __restrict__ params, int ceoff,
                            float* __restrict__ s) {
    int n = blockIdx.x * blockDim.x + threadIdx.x;
    if (n >= N_NODES) return;
    float eam = params[1];
    float2 as = ((const float2*)asrc)[n];
    float2 ad = ((const float2*)adst)[n];
    float a0 = lrelu(as.x + ad.x + params[ceoff] * eam);
    float a1 = lrelu(as.y + ad.y + params[ceoff + 1] * eam);
    ((float2*)s)[n] = make_float2(__expf(a0), __expf(a1));
}

__global__ void k_edge_pass1(const int* __restrict__ src, const int* __restrict__ dst,
                             const float* __restrict__ ea,
                             const float* __restrict__ asrc, const float* __restrict__ adst,
                             const float* __restrict__ params, int ceoff,
                             float* __restrict__ s, float* __restrict__ w) {
    int e = blockIdx.x * blockDim.x + threadIdx.x;
    if (e >= N_EDGES) return;
    int sv = src[e], dv = dst[e];
    float eav = ea[e];
    float2 as = ((const float2*)asrc)[sv];
    float2 ad = ((const float2*)adst)[dv];
    float w0 = __expf(lrelu(as.x + ad.x + params[ceoff] * eav));
    float w1 = __expf(lrelu(as.y + ad.y + params[ceoff + 1] * eav));
    ((float2*)w)[e] = make_float2(w0, w1);
    unsafeAtomicAdd(&s[dv * 2 + 0], w0);
    unsafeAtomicAdd(&s[dv * 2 + 1], w1);
}

// ---------- message scatter: 32 lanes per edge ----------

__global__ void k_edge_pass2(const int* __restrict__ src, const int* __restrict__ dst,
                             const float* __restrict__ w, const float* __restrict__ s,
                             const float* __restrict__ h, float* __restrict__ acc) {
    unsigned tid = blockIdx.x * blockDim.x + threadIdx.x;
    int e = (int)(tid >> 5);
    if (e >= N_EDGES) return;
    int c = (int)(tid & 31);
    int hh = c >> 4;
    int sv = src[e], dv = dst[e];
    float att = w[e * 2 + hh] / (s[dv * 2 + hh] + 1e-16f);
    unsafeAtomicAdd(&acc[(size_t)dv * HC + c], h[(size_t)sv * HC + c] * att);
}

// ---------- self-message + bias (+relu), in place on acc ----------

__global__ void k_finalize(const float* __restrict__ asrc, const float* __restrict__ adst,
                           const float* __restrict__ s, const float* __restrict__ h,
                           const float* __restrict__ bias, const float* __restrict__ params,
                           int ceoff, int do_relu, float* __restrict__ acc) {
    int tid = blockIdx.x * blockDim.x + threadIdx.x;
    int n = tid >> 5;
    if (n >= N_NODES) return;
    int c = tid & 31, hh = c >> 4;
    float a = asrc[n * 2 + hh] + adst[n * 2 + hh] + params[ceoff + hh] * params[1];
    float att = __expf(lrelu(a)) / (s[n * 2 + hh] + 1e-16f);
    float v = acc[(size_t)n * HC + c] + h[(size_t)n * HC + c] * att + bias[c];
    if (do_relu) v = fmaxf(v, 0.f);
    acc[(size_t)n * HC + c] = v;
}

// ---------- batch pooling (batch is sorted) ----------

__global__ void k_bounds(const int* __restrict__ batch, int* __restrict__ se) {
    int i = blockIdx.x * blockDim.x + threadIdx.x;
    if (i >= N_NODES) return;
    int b = batch[i];
    if (i == 0 || batch[i - 1] != b) se[b] = i;
    if (i == N_NODES - 1 || batch[i + 1] != b) se[NGRAPH + b] = i + 1;
}

__global__ void k_pool(const float* __restrict__ feat, const int* __restrict__ se,
                       float* __restrict__ emb) {
    int g = blockIdx.x;
    int st = se[g], en = se[NGRAPH + g];
    int c = threadIdx.x & 31, r = threadIdx.x >> 5;  // r in 0..7
    float acc = 0.f;
    for (int n = st + r; n < en; n += 8) acc += feat[(size_t)n * HC + c];
    __shared__ float sh[8][32];
    sh[r][c] = acc;
    __syncthreads();
    if (threadIdx.x < 32) {
        float t = 0.f;
        for (int r2 = 0; r2 < 8; ++r2) t += sh[r2][c];
        int cnt = en - st;
        emb[g * HC + c] = t / (float)(cnt > 0 ? cnt : 1);
    }
}

// ---------- tiny MLP head ----------

__global__ void k_mlp(const float* __restrict__ emb, const float* __restrict__ Wf1,
                      const float* __restrict__ bf1, const float* __restrict__ Wf2,
                      const float* __restrict__ bf2, float* __restrict__ out) {
    int g = blockIdx.x, j = threadIdx.x;  // 32 threads
    __shared__ float hid[32];
    float a = bf1[j];
    for (int k = 0; k < 32; ++k) a = fmaf(emb[g * 32 + k], Wf1[k * 32 + j], a);
    hid[j] = fmaxf(a, 0.f);
    __syncthreads();
    if (j < 2) {
        float o = bf2[j];
        for (int k = 0; k < 32; ++k) o = fmaf(hid[k], Wf2[k * 2 + j], o);
        out[g * 2 + j] = o;
    }
}

extern "C" void kernel_launch(void* const* d_in, const int* in_sizes, int n_in,
                              void* d_out, int out_size, void* d_ws, size_t ws_size,
                              hipStream_t stream) {
    const float* x   = (const float*)d_in[0];
    const int*   ei  = (const int*)d_in[1];
    const float* ea  = (const float*)d_in[2];
    const int* batch = (const int*)d_in[3];
    const float* W1  = (const float*)d_in[4];
    const float* as1 = (const float*)d_in[5];
    const float* ad1 = (const float*)d_in[6];
    const float* We1 = (const float*)d_in[7];
    const float* ae1 = (const float*)d_in[8];
    const float* b1  = (const float*)d_in[9];
    const float* W2  = (const float*)d_in[10];
    const float* as2 = (const float*)d_in[11];
    const float* ad2 = (const float*)d_in[12];
    const float* We2 = (const float*)d_in[13];
    const float* ae2 = (const float*)d_in[14];
    const float* b2  = (const float*)d_in[15];
    const float* Wf1 = (const float*)d_in[16];
    const float* bf1 = (const float*)d_in[17];
    const float* Wf2 = (const float*)d_in[18];
    const float* bf2 = (const float*)d_in[19];
    float* out = (float*)d_out;
    (void)in_sizes; (void)n_in; (void)out_size; (void)ws_size;

    const int* srcp = ei;
    const int* dstp = ei + N_EDGES;

    char* wsb = (char*)d_ws;
    size_t off = 0;
    auto alloc = [&](size_t bytes) -> char* {
        char* p = wsb + off;
        off = (off + bytes + 255) & ~(size_t)255;
        return p;
    };
    float* params = (float*)alloc(64);
    float* hbuf   = (float*)alloc((size_t)N_NODES * HC * 4);
    float* accb   = (float*)alloc((size_t)N_NODES * HC * 4);
    float* asrc   = (float*)alloc((size_t)N_NODES * 2 * 4);
    float* adst   = (float*)alloc((size_t)N_NODES * 2 * 4);
    float* sbuf   = (float*)alloc((size_t)N_NODES * 2 * 4);
    float* wbuf   = (float*)alloc((size_t)N_EDGES * 2 * 4);
    float* emb    = (float*)alloc(NGRAPH * HC * 4);
    int*   se     = (int*)alloc(2 * NGRAPH * 4);

    hipMemsetAsync(params, 0, 64, stream);
    hipMemsetAsync(se, 0, 2 * NGRAPH * 4, stream);

    k_ea_sum<<<1024, 256, 0, stream>>>(ea, params);
    k_prep<<<1, 64, 0, stream>>>(We1, ae1, We2, ae2, params);

    const int nThr = N_NODES * HC;  // 3.2M
    const int nBlk = (nThr + 255) / 256;
    const int nBlkN = (N_NODES + 255) / 256;
    const int nBlkE = (N_EDGES + 255) / 256;
    const unsigned nBlkE32 = (unsigned)(((long long)N_EDGES * 32 + 255) / 256);

    k_linear<F_IN><<<nBlk, 256, 0, stream>>>(x, W1, as1, ad1, hbuf, asrc, adst);

    // ----- layer 1 -----
    hipMemsetAsync(accb, 0, (size_t)N_NODES * HC * 4, stream);
    k_self_init<<<nBlkN, 256, 0, stream>>>(asrc, adst, params, 2, sbuf);
    k_edge_pass1<<<nBlkE, 256, 0, stream>>>(srcp, dstp, ea, asrc, adst, params, 2, sbuf, wbuf);
    k_edge_pass2<<<nBlkE32, 256, 0, stream>>>(srcp, dstp, wbuf, sbuf, hbuf, accb);
    k_finalize<<<nBlk, 256, 0, stream>>>(asrc, adst, sbuf, hbuf, b1, params, 2, 1, accb);

    // ----- linear 2 (reads accb, writes hbuf/asrc/adst) -----
    k_linear<HC><<<nBlk, 256, 0, stream>>>(accb, W2, as2, ad2, hbuf, asrc, adst);

    // ----- layer 2 -----
    hipMemsetAsync(accb, 0, (size_t)N_NODES * HC * 4, stream);
    k_self_init<<<nBlkN, 256, 0, stream>>>(asrc, adst, params, 4, sbuf);
    k_edge_pass1<<<nBlkE, 256, 0, stream>>>(srcp, dstp, ea, asrc, adst, params, 4, sbuf, wbuf);
    k_edge_pass2<<<nBlkE32, 256, 0, stream>>>(srcp, dstp, wbuf, sbuf, hbuf, accb);
    k_finalize<<<nBlk, 256, 0, stream>>>(asrc, adst, sbuf, hbuf, b2, params, 4, 0, accb);

    // ----- pool + MLP -----
    k_bounds<<<nBlkN, 256, 0, stream>>>(batch, se);
    k_pool<<<NGRAPH, 256, 0, stream>>>(accb, se, emb);
    k_mlp<<<NGRAPH, 32, 0, stream>>>(emb, Wf1, bf1, Wf2, bf2, out);
}

// Round 2
// 1084.486 us; speedup vs baseline: 1.5426x; 1.5426x over previous
//
#include <hip/hip_runtime.h>

#define N_NODES 100000
#define N_EDGES 3200000
#define F_IN    128
#define HC      32      // H*C
#define CH      16      // C per head
#define NGRAPH  64
#define NEG     0.2f

#define SCAN_CHUNK 512
#define NSCB ((N_NODES + SCAN_CHUNK - 1) / SCAN_CHUNK)   // 196

__device__ __forceinline__ float lrelu(float x) { return x > 0.f ? x : NEG * x; }

// ---------- reductions / small precompute ----------

__global__ void k_ea_sum(const float* __restrict__ ea, float* __restrict__ params) {
    float acc = 0.f;
    for (int i = blockIdx.x * blockDim.x + threadIdx.x; i < N_EDGES;
         i += gridDim.x * blockDim.x)
        acc += ea[i];
    for (int m = 32; m >= 1; m >>= 1) acc += __shfl_xor(acc, m, 64);
    __shared__ float sh[4];
    int lane = threadIdx.x & 63, wid = threadIdx.x >> 6;
    if (lane == 0) sh[wid] = acc;
    __syncthreads();
    if (threadIdx.x == 0) {
        float t = 0.f;
        for (int i = 0; i < 4; ++i) t += sh[i];
        unsafeAtomicAdd(params, t);
    }
}

// params: [0]=ea_sum, [1]=ea_mean, [2..3]=ce layer1, [4..5]=ce layer2
__global__ void k_prep(const float* __restrict__ We1, const float* __restrict__ ae1,
                       const float* __restrict__ We2, const float* __restrict__ ae2,
                       float* __restrict__ params) {
    int t = threadIdx.x;
    if (t < 2) {
        float c1 = 0.f, c2 = 0.f;
        for (int c = 0; c < CH; ++c) {
            c1 += We1[t * CH + c] * ae1[t * CH + c];
            c2 += We2[t * CH + c] * ae2[t * CH + c];
        }
        params[2 + t] = c1;
        params[4 + t] = c2;
        if (t == 0) params[1] = params[0] / (float)N_EDGES;
    }
}

// ---------- CSR build: histogram -> scan -> fill ----------

__global__ void k_hist(const int* __restrict__ dst, int* __restrict__ cnt) {
    for (int e = blockIdx.x * blockDim.x + threadIdx.x; e < N_EDGES;
         e += gridDim.x * blockDim.x)
        atomicAdd(&cnt[dst[e]], 1);
}

__global__ void k_scan1(const int* __restrict__ cnt, int* __restrict__ bsum) {
    int b = blockIdx.x, t = threadIdx.x;
    int i0 = b * SCAN_CHUNK + 2 * t;
    int v0 = (i0 < N_NODES) ? cnt[i0] : 0;
    int v1 = (i0 + 1 < N_NODES) ? cnt[i0 + 1] : 0;
    int ts = v0 + v1;
    for (int m = 32; m >= 1; m >>= 1) ts += __shfl_xor(ts, m, 64);
    __shared__ int sh[4];
    if ((t & 63) == 0) sh[t >> 6] = ts;
    __syncthreads();
    if (t == 0) bsum[b] = sh[0] + sh[1] + sh[2] + sh[3];
}

__global__ void k_scan2(const int* __restrict__ bsum, int* __restrict__ boff) {
    int t = threadIdx.x;
    __shared__ int sh[256];
    int v = (t < NSCB) ? bsum[t] : 0;
    sh[t] = v;
    __syncthreads();
    for (int off = 1; off < 256; off <<= 1) {
        int u = (t >= off) ? sh[t - off] : 0;
        __syncthreads();
        sh[t] += u;
        __syncthreads();
    }
    if (t < NSCB) boff[t] = sh[t] - v;   // exclusive
}

__global__ void k_scan3(const int* __restrict__ cnt, const int* __restrict__ boff,
                        int* __restrict__ rowptr) {
    int b = blockIdx.x, t = threadIdx.x;
    int i0 = b * SCAN_CHUNK + 2 * t;
    int c0 = (i0 < N_NODES) ? cnt[i0] : 0;
    int c1 = (i0 + 1 < N_NODES) ? cnt[i0 + 1] : 0;
    int ts = c0 + c1;
    __shared__ int sh[256];
    sh[t] = ts;
    __syncthreads();
    for (int off = 1; off < 256; off <<= 1) {
        int u = (t >= off) ? sh[t - off] : 0;
        __syncthreads();
        sh[t] += u;
        __syncthreads();
    }
    int g = boff[b] + (sh[t] - ts);      // exclusive within block
    if (i0 < N_NODES) rowptr[i0] = g;
    if (i0 + 1 < N_NODES) rowptr[i0 + 1] = g + c0;
    if (b == 0 && t == 0) rowptr[N_NODES] = N_EDGES;
}

__global__ void k_fill(const int* __restrict__ src, const int* __restrict__ dst,
                       const float* __restrict__ ea, int* __restrict__ cursor,
                       int* __restrict__ esrc, float* __restrict__ eas) {
    int e = blockIdx.x * blockDim.x + threadIdx.x;
    if (e >= N_EDGES) return;
    int dv = dst[e];
    int pos = atomicAdd(&cursor[dv], 1);
    esrc[pos] = src[e];
    eas[pos] = ea[e];
}

// ---------- dense: h = x @ W, plus fused asrc/adst ----------

template <int FIN>
__global__ void k_linear(const float* __restrict__ x, const float* __restrict__ W,
                         const float* __restrict__ a_src, const float* __restrict__ a_dst,
                         float* __restrict__ h, float* __restrict__ asrc,
                         float* __restrict__ adst) {
    int tid = blockIdx.x * blockDim.x + threadIdx.x;
    int n = tid >> 5;
    if (n >= N_NODES) return;
    int c = tid & 31;
    const float* xr = x + (size_t)n * FIN;
    float acc = 0.f;
#pragma unroll 8
    for (int k = 0; k < FIN; ++k) acc = fmaf(xr[k], W[k * HC + c], acc);
    h[(size_t)n * HC + c] = acc;
    int hh = c >> 4, cc = c & 15;
    float vs = acc * a_src[hh * CH + cc];
    float vd = acc * a_dst[hh * CH + cc];
    for (int m = 8; m >= 1; m >>= 1) {
        vs += __shfl_xor(vs, m, 16);
        vd += __shfl_xor(vd, m, 16);
    }
    if (cc == 0) {
        asrc[n * 2 + hh] = vs;
        adst[n * 2 + hh] = vd;
    }
}

// ---------- fused GAT layer: gather form, no atomics ----------
// out[n,c] = (sum_e w_e * h[src_e, c] + w_self * h[n,c]) / (sum w + eps) + bias

__global__ void k_gat(const int* __restrict__ rowptr, const int* __restrict__ esrc,
                      const float* __restrict__ eas, const float* __restrict__ h,
                      const float* __restrict__ asrc, const float* __restrict__ adst,
                      const float* __restrict__ params, int ceoff,
                      const float* __restrict__ bias, int do_relu,
                      float* __restrict__ out) {
    int tid = blockIdx.x * blockDim.x + threadIdx.x;
    int n = tid >> 5;
    if (n >= N_NODES) return;
    int c = tid & 31, hh = c >> 4;
    int st = rowptr[n], en = rowptr[n + 1];
    float ce = params[ceoff + hh];
    float adn = adst[n * 2 + hh];
    float acc = 0.f, ssum = 0.f;
    for (int e = st; e < en; ++e) {
        int sv = esrc[e];
        float eav = eas[e];
        float asv = asrc[sv * 2 + hh];
        float hv = h[(size_t)sv * HC + c];
        float wv = __expf(lrelu(asv + adn + ce * eav));
        acc = fmaf(wv, hv, acc);
        ssum += wv;
    }
    // self-loop (eattr = mean)
    float wself = __expf(lrelu(asrc[n * 2 + hh] + adn + ce * params[1]));
    acc = fmaf(wself, h[(size_t)n * HC + c], acc);
    ssum += wself;
    float v = acc / (ssum + 1e-16f) + bias[c];
    if (do_relu) v = fmaxf(v, 0.f);
    out[(size_t)n * HC + c] = v;
}

// ---------- batch pooling (batch is sorted) ----------

__global__ void k_bounds(const int* __restrict__ batch, int* __restrict__ se) {
    int i = blockIdx.x * blockDim.x + threadIdx.x;
    if (i >= N_NODES) return;
    int b = batch[i];
    if (i == 0 || batch[i - 1] != b) se[b] = i;
    if (i == N_NODES - 1 || batch[i + 1] != b) se[NGRAPH + b] = i + 1;
}

__global__ void k_pool(const float* __restrict__ feat, const int* __restrict__ se,
                       float* __restrict__ emb) {
    int g = blockIdx.x;
    int st = se[g], en = se[NGRAPH + g];
    int c = threadIdx.x & 31, r = threadIdx.x >> 5;  // r in 0..7
    float acc = 0.f;
    for (int n = st + r; n < en; n += 8) acc += feat[(size_t)n * HC + c];
    __shared__ float sh[8][32];
    sh[r][c] = acc;
    __syncthreads();
    if (threadIdx.x < 32) {
        float t = 0.f;
        for (int r2 = 0; r2 < 8; ++r2) t += sh[r2][c];
        int cnt = en - st;
        emb[g * HC + c] = t / (float)(cnt > 0 ? cnt : 1);
    }
}

// ---------- tiny MLP head ----------

__global__ void k_mlp(const float* __restrict__ emb, const float* __restrict__ Wf1,
                      const float* __restrict__ bf1, const float* __restrict__ Wf2,
                      const float* __restrict__ bf2, float* __restrict__ out) {
    int g = blockIdx.x, j = threadIdx.x;  // 32 threads
    __shared__ float hid[32];
    float a = bf1[j];
    for (int k = 0; k < 32; ++k) a = fmaf(emb[g * 32 + k], Wf1[k * 32 + j], a);
    hid[j] = fmaxf(a, 0.f);
    __syncthreads();
    if (j < 2) {
        float o = bf2[j];
        for (int k = 0; k < 32; ++k) o = fmaf(hid[k], Wf2[k * 2 + j], o);
        out[g * 2 + j] = o;
    }
}

extern "C" void kernel_launch(void* const* d_in, const int* in_sizes, int n_in,
                              void* d_out, int out_size, void* d_ws, size_t ws_size,
                              hipStream_t stream) {
    const float* x   = (const float*)d_in[0];
    const int*   ei  = (const int*)d_in[1];
    const float* ea  = (const float*)d_in[2];
    const int* batch = (const int*)d_in[3];
    const float* W1  = (const float*)d_in[4];
    const float* as1 = (const float*)d_in[5];
    const float* ad1 = (const float*)d_in[6];
    const float* We1 = (const float*)d_in[7];
    const float* ae1 = (const float*)d_in[8];
    const float* b1  = (const float*)d_in[9];
    const float* W2  = (const float*)d_in[10];
    const float* as2 = (const float*)d_in[11];
    const float* ad2 = (const float*)d_in[12];
    const float* We2 = (const float*)d_in[13];
    const float* ae2 = (const float*)d_in[14];
    const float* b2  = (const float*)d_in[15];
    const float* Wf1 = (const float*)d_in[16];
    const float* bf1 = (const float*)d_in[17];
    const float* Wf2 = (const float*)d_in[18];
    const float* bf2 = (const float*)d_in[19];
    float* out = (float*)d_out;
    (void)in_sizes; (void)n_in; (void)out_size; (void)ws_size;

    const int* srcp = ei;
    const int* dstp = ei + N_EDGES;

    char* wsb = (char*)d_ws;
    size_t off = 0;
    auto alloc = [&](size_t bytes) -> char* {
        char* p = wsb + off;
        off = (off + bytes + 255) & ~(size_t)255;
        return p;
    };
    float* params = (float*)alloc(64);
    float* hbuf   = (float*)alloc((size_t)N_NODES * HC * 4);
    float* obuf   = (float*)alloc((size_t)N_NODES * HC * 4);
    float* asrc   = (float*)alloc((size_t)N_NODES * 2 * 4);
    float* adst   = (float*)alloc((size_t)N_NODES * 2 * 4);
    int*   cnt    = (int*)alloc((size_t)N_NODES * 4);
    int*   cursor = (int*)alloc((size_t)N_NODES * 4);
    int*   rowptr = (int*)alloc((size_t)(N_NODES + 1) * 4);
    int*   bsum   = (int*)alloc(NSCB * 4);
    int*   boff   = (int*)alloc(NSCB * 4);
    int*   esrc   = (int*)alloc((size_t)N_EDGES * 4);
    float* eas    = (float*)alloc((size_t)N_EDGES * 4);
    float* emb    = (float*)alloc(NGRAPH * HC * 4);
    int*   se     = (int*)alloc(2 * NGRAPH * 4);

    hipMemsetAsync(params, 0, 64, stream);
    hipMemsetAsync(cnt, 0, (size_t)N_NODES * 4, stream);
    hipMemsetAsync(se, 0, 2 * NGRAPH * 4, stream);

    const int nThr = N_NODES * HC;  // 3.2M
    const int nBlk = (nThr + 255) / 256;
    const int nBlkN = (N_NODES + 255) / 256;
    const int nBlkE = (N_EDGES + 255) / 256;

    // small precompute + CSR build
    k_ea_sum<<<1024, 256, 0, stream>>>(ea, params);
    k_prep<<<1, 64, 0, stream>>>(We1, ae1, We2, ae2, params);
    k_hist<<<2048, 256, 0, stream>>>(dstp, cnt);
    k_scan1<<<NSCB, 256, 0, stream>>>(cnt, bsum);
    k_scan2<<<1, 256, 0, stream>>>(bsum, boff);
    k_scan3<<<NSCB, 256, 0, stream>>>(cnt, boff, rowptr);
    hipMemcpyAsync(cursor, rowptr, (size_t)N_NODES * 4, hipMemcpyDeviceToDevice, stream);
    k_fill<<<nBlkE, 256, 0, stream>>>(srcp, dstp, ea, cursor, esrc, eas);

    // ----- layer 1 -----
    k_linear<F_IN><<<nBlk, 256, 0, stream>>>(x, W1, as1, ad1, hbuf, asrc, adst);
    k_gat<<<nBlk, 256, 0, stream>>>(rowptr, esrc, eas, hbuf, asrc, adst, params, 2, b1, 1, obuf);

    // ----- layer 2 -----
    k_linear<HC><<<nBlk, 256, 0, stream>>>(obuf, W2, as2, ad2, hbuf, asrc, adst);
    k_gat<<<nBlk, 256, 0, stream>>>(rowptr, esrc, eas, hbuf, asrc, adst, params, 4, b2, 0, obuf);

    // ----- pool + MLP -----
    k_bounds<<<nBlkN, 256, 0, stream>>>(batch, se);
    k_pool<<<NGRAPH, 256, 0, stream>>>(obuf, se, emb);
    k_mlp<<<NGRAPH, 32, 0, stream>>>(emb, Wf1, bf1, Wf2, bf2, out);
}

// Round 3
// 958.292 us; speedup vs baseline: 1.7457x; 1.1317x over previous
//
#include <hip/hip_runtime.h>

#define N_NODES 100000
#define N_EDGES 3200000
#define F_IN    128
#define HC      32      // H*C
#define CH      16      // C per head
#define NGRAPH  64
#define NEG     0.2f

#define SCAN_CHUNK 512
#define NSCB ((N_NODES + SCAN_CHUNK - 1) / SCAN_CHUNK)   // 196
#define NBUCK ((N_NODES + 511) >> 9)                      // 196 buckets of 512 nodes
#define EPB 4096                                          // edges per bucket-pass block

__device__ __forceinline__ float lrelu(float x) { return x > 0.f ? x : NEG * x; }

// ---------- reductions / small precompute ----------

__global__ void k_ea_sum(const float* __restrict__ ea, float* __restrict__ params) {
    float acc = 0.f;
    for (int i = blockIdx.x * blockDim.x + threadIdx.x; i < N_EDGES;
         i += gridDim.x * blockDim.x)
        acc += ea[i];
    for (int m = 32; m >= 1; m >>= 1) acc += __shfl_xor(acc, m, 64);
    __shared__ float sh[4];
    int lane = threadIdx.x & 63, wid = threadIdx.x >> 6;
    if (lane == 0) sh[wid] = acc;
    __syncthreads();
    if (threadIdx.x == 0) {
        float t = 0.f;
        for (int i = 0; i < 4; ++i) t += sh[i];
        unsafeAtomicAdd(params, t);
    }
}

// params: [0]=ea_sum, [1]=ea_mean, [2..3]=ce layer1, [4..5]=ce layer2
__global__ void k_prep(const float* __restrict__ We1, const float* __restrict__ ae1,
                       const float* __restrict__ We2, const float* __restrict__ ae2,
                       float* __restrict__ params) {
    int t = threadIdx.x;
    if (t < 2) {
        float c1 = 0.f, c2 = 0.f;
        for (int c = 0; c < CH; ++c) {
            c1 += We1[t * CH + c] * ae1[t * CH + c];
            c2 += We2[t * CH + c] * ae2[t * CH + c];
        }
        params[2 + t] = c1;
        params[4 + t] = c2;
        if (t == 0) params[1] = params[0] / (float)N_EDGES;
    }
}

// ---------- CSR build: histogram -> scan ----------

__global__ void k_hist(const int* __restrict__ dst, int* __restrict__ cnt) {
    for (int e = blockIdx.x * blockDim.x + threadIdx.x; e < N_EDGES;
         e += gridDim.x * blockDim.x)
        atomicAdd(&cnt[dst[e]], 1);
}

__global__ void k_scan1(const int* __restrict__ cnt, int* __restrict__ bsum) {
    int b = blockIdx.x, t = threadIdx.x;
    int i0 = b * SCAN_CHUNK + 2 * t;
    int v0 = (i0 < N_NODES) ? cnt[i0] : 0;
    int v1 = (i0 + 1 < N_NODES) ? cnt[i0 + 1] : 0;
    int ts = v0 + v1;
    for (int m = 32; m >= 1; m >>= 1) ts += __shfl_xor(ts, m, 64);
    __shared__ int sh[4];
    if ((t & 63) == 0) sh[t >> 6] = ts;
    __syncthreads();
    if (t == 0) bsum[b] = sh[0] + sh[1] + sh[2] + sh[3];
}

__global__ void k_scan2(const int* __restrict__ bsum, int* __restrict__ boff) {
    int t = threadIdx.x;
    __shared__ int sh[256];
    int v = (t < NSCB) ? bsum[t] : 0;
    sh[t] = v;
    __syncthreads();
    for (int off = 1; off < 256; off <<= 1) {
        int u = (t >= off) ? sh[t - off] : 0;
        __syncthreads();
        sh[t] += u;
        __syncthreads();
    }
    if (t < NSCB) boff[t] = sh[t] - v;   // exclusive
}

__global__ void k_scan3(const int* __restrict__ cnt, const int* __restrict__ boff,
                        int* __restrict__ rowptr) {
    int b = blockIdx.x, t = threadIdx.x;
    int i0 = b * SCAN_CHUNK + 2 * t;
    int c0 = (i0 < N_NODES) ? cnt[i0] : 0;
    int c1 = (i0 + 1 < N_NODES) ? cnt[i0 + 1] : 0;
    int ts = c0 + c1;
    __shared__ int sh[256];
    sh[t] = ts;
    __syncthreads();
    for (int off = 1; off < 256; off <<= 1) {
        int u = (t >= off) ? sh[t - off] : 0;
        __syncthreads();
        sh[t] += u;
        __syncthreads();
    }
    int g = boff[b] + (sh[t] - ts);      // exclusive within block
    if (i0 < N_NODES) rowptr[i0] = g;
    if (i0 + 1 < N_NODES) rowptr[i0 + 1] = g + c0;
    if (b == 0 && t == 0) rowptr[N_NODES] = N_EDGES;
}

__global__ void k_gcur_init(const int* __restrict__ rowptr, int* __restrict__ gcur) {
    int b = threadIdx.x;
    if (b < NBUCK) {
        int n = b << 9;
        gcur[b] = rowptr[n < N_NODES ? n : N_NODES];
    }
}

// ---------- pass A: bucket scatter (coalesced per-bucket runs) ----------

__global__ void k_bucket(const int* __restrict__ src, const int* __restrict__ dst,
                         const float* __restrict__ ea, int* __restrict__ gcur,
                         int2* __restrict__ staged, int* __restrict__ sdst) {
    __shared__ int lcur[256];
    __shared__ int gbase[256];
    int t = threadIdx.x;
    lcur[t] = 0;
    __syncthreads();
    int base = blockIdx.x * EPB;
    int rank[EPB / 256];
#pragma unroll
    for (int i = 0; i < EPB / 256; ++i) {
        int e = base + i * 256 + t;
        if (e < N_EDGES) rank[i] = atomicAdd(&lcur[dst[e] >> 9], 1);
    }
    __syncthreads();
    if (t < NBUCK && lcur[t] > 0) gbase[t] = atomicAdd(&gcur[t], lcur[t]);
    __syncthreads();
#pragma unroll
    for (int i = 0; i < EPB / 256; ++i) {
        int e = base + i * 256 + t;
        if (e < N_EDGES) {
            int dv = dst[e];
            int pos = gbase[dv >> 9] + rank[i];
            staged[pos] = make_int2(src[e], __float_as_int(ea[e]));
            sdst[pos] = dv;
        }
    }
}

// ---------- pass B: in-bucket fine scatter, one block per bucket ----------

__global__ void k_scatter(const int2* __restrict__ staged, const int* __restrict__ sdst,
                          const int* __restrict__ rowptr, int2* __restrict__ epack) {
    int b = blockIdx.x;
    int nbase = b << 9;
    __shared__ int lcur[512];
    for (int i = threadIdx.x; i < 512; i += 256) {
        int n = nbase + i;
        lcur[i] = rowptr[n < N_NODES ? n : N_NODES];
    }
    __syncthreads();
    int nend = nbase + 512;
    if (nend > N_NODES) nend = N_NODES;
    int st = rowptr[nbase], en = rowptr[nend];
    for (int e = st + threadIdx.x; e < en; e += 256) {
        int2 r = staged[e];
        int dv = sdst[e];
        int pos = atomicAdd(&lcur[dv - nbase], 1);
        epack[pos] = r;
    }
}

// ---------- dense: h = x @ W, plus fused asrc/adst ----------

template <int FIN>
__global__ void k_linear(const float* __restrict__ x, const float* __restrict__ W,
                         const float* __restrict__ a_src, const float* __restrict__ a_dst,
                         float* __restrict__ h, float* __restrict__ asrc,
                         float* __restrict__ adst) {
    int tid = blockIdx.x * blockDim.x + threadIdx.x;
    int n = tid >> 5;
    if (n >= N_NODES) return;
    int c = tid & 31;
    const float* xr = x + (size_t)n * FIN;
    float acc = 0.f;
#pragma unroll 8
    for (int k = 0; k < FIN; ++k) acc = fmaf(xr[k], W[k * HC + c], acc);
    h[(size_t)n * HC + c] = acc;
    int hh = c >> 4, cc = c & 15;
    float vs = acc * a_src[hh * CH + cc];
    float vd = acc * a_dst[hh * CH + cc];
    for (int m = 8; m >= 1; m >>= 1) {
        vs += __shfl_xor(vs, m, 16);
        vd += __shfl_xor(vd, m, 16);
    }
    if (cc == 0) {
        asrc[n * 2 + hh] = vs;
        adst[n * 2 + hh] = vd;
    }
}

// ---------- fused GAT layer: gather form, no atomics ----------

__global__ void k_gat(const int* __restrict__ rowptr, const int2* __restrict__ epack,
                      const float* __restrict__ h,
                      const float* __restrict__ asrc, const float* __restrict__ adst,
                      const float* __restrict__ params, int ceoff,
                      const float* __restrict__ bias, int do_relu,
                      float* __restrict__ out) {
    int tid = blockIdx.x * blockDim.x + threadIdx.x;
    int n = tid >> 5;
    if (n >= N_NODES) return;
    int c = tid & 31, hh = c >> 4;
    int st = rowptr[n], en = rowptr[n + 1];
    float ce = params[ceoff + hh];
    float adn = adst[n * 2 + hh];
    float acc = 0.f, ssum = 0.f;
    for (int e = st; e < en; ++e) {
        int2 r = epack[e];
        int sv = r.x;
        float eav = __int_as_float(r.y);
        float asv = asrc[sv * 2 + hh];
        float hv = h[(size_t)sv * HC + c];
        float wv = __expf(lrelu(asv + adn + ce * eav));
        acc = fmaf(wv, hv, acc);
        ssum += wv;
    }
    // self-loop (eattr = mean)
    float wself = __expf(lrelu(asrc[n * 2 + hh] + adn + ce * params[1]));
    acc = fmaf(wself, h[(size_t)n * HC + c], acc);
    ssum += wself;
    float v = acc / (ssum + 1e-16f) + bias[c];
    if (do_relu) v = fmaxf(v, 0.f);
    out[(size_t)n * HC + c] = v;
}

// ---------- batch pooling (batch is sorted) ----------

__global__ void k_bounds(const int* __restrict__ batch, int* __restrict__ se) {
    int i = blockIdx.x * blockDim.x + threadIdx.x;
    if (i >= N_NODES) return;
    int b = batch[i];
    if (i == 0 || batch[i - 1] != b) se[b] = i;
    if (i == N_NODES - 1 || batch[i + 1] != b) se[NGRAPH + b] = i + 1;
}

__global__ void k_pool(const float* __restrict__ feat, const int* __restrict__ se,
                       float* __restrict__ emb) {
    int g = blockIdx.x;
    int st = se[g], en = se[NGRAPH + g];
    int c = threadIdx.x & 31, r = threadIdx.x >> 5;  // r in 0..7
    float acc = 0.f;
    for (int n = st + r; n < en; n += 8) acc += feat[(size_t)n * HC + c];
    __shared__ float sh[8][32];
    sh[r][c] = acc;
    __syncthreads();
    if (threadIdx.x < 32) {
        float t = 0.f;
        for (int r2 = 0; r2 < 8; ++r2) t += sh[r2][c];
        int cnt = en - st;
        emb[g * HC + c] = t / (float)(cnt > 0 ? cnt : 1);
    }
}

// ---------- tiny MLP head ----------

__global__ void k_mlp(const float* __restrict__ emb, const float* __restrict__ Wf1,
                      const float* __restrict__ bf1, const float* __restrict__ Wf2,
                      const float* __restrict__ bf2, float* __restrict__ out) {
    int g = blockIdx.x, j = threadIdx.x;  // 32 threads
    __shared__ float hid[32];
    float a = bf1[j];
    for (int k = 0; k < 32; ++k) a = fmaf(emb[g * 32 + k], Wf1[k * 32 + j], a);
    hid[j] = fmaxf(a, 0.f);
    __syncthreads();
    if (j < 2) {
        float o = bf2[j];
        for (int k = 0; k < 32; ++k) o = fmaf(hid[k], Wf2[k * 2 + j], o);
        out[g * 2 + j] = o;
    }
}

extern "C" void kernel_launch(void* const* d_in, const int* in_sizes, int n_in,
                              void* d_out, int out_size, void* d_ws, size_t ws_size,
                              hipStream_t stream) {
    const float* x   = (const float*)d_in[0];
    const int*   ei  = (const int*)d_in[1];
    const float* ea  = (const float*)d_in[2];
    const int* batch = (const int*)d_in[3];
    const float* W1  = (const float*)d_in[4];
    const float* as1 = (const float*)d_in[5];
    const float* ad1 = (const float*)d_in[6];
    const float* We1 = (const float*)d_in[7];
    const float* ae1 = (const float*)d_in[8];
    const float* b1  = (const float*)d_in[9];
    const float* W2  = (const float*)d_in[10];
    const float* as2 = (const float*)d_in[11];
    const float* ad2 = (const float*)d_in[12];
    const float* We2 = (const float*)d_in[13];
    const float* ae2 = (const float*)d_in[14];
    const float* b2  = (const float*)d_in[15];
    const float* Wf1 = (const float*)d_in[16];
    const float* bf1 = (const float*)d_in[17];
    const float* Wf2 = (const float*)d_in[18];
    const float* bf2 = (const float*)d_in[19];
    float* out = (float*)d_out;
    (void)in_sizes; (void)n_in; (void)out_size; (void)ws_size;

    const int* srcp = ei;
    const int* dstp = ei + N_EDGES;

    char* wsb = (char*)d_ws;
    size_t off = 0;
    auto alloc = [&](size_t bytes) -> char* {
        char* p = wsb + off;
        off = (off + bytes + 255) & ~(size_t)255;
        return p;
    };
    float* params = (float*)alloc(64);
    // region A: staged (25.6 MB) + sdst (12.8 MB) reused later as hbuf/obuf/asrc/adst
    char* regA = alloc((size_t)N_EDGES * 8 + (size_t)N_EDGES * 4 + 4096);
    int2*  staged = (int2*)regA;
    int*   sdst   = (int*)(regA + (size_t)N_EDGES * 8);
    float* hbuf   = (float*)regA;                                   // 12.8 MB
    float* obuf   = (float*)(regA + (size_t)N_NODES * HC * 4);      // 12.8 MB
    float* asrc   = (float*)(regA + (size_t)N_NODES * HC * 8);      // 0.8 MB
    float* adst   = (float*)(regA + (size_t)N_NODES * HC * 8 + (size_t)N_NODES * 8);
    int2*  epack  = (int2*)alloc((size_t)N_EDGES * 8);
    int*   cnt    = (int*)alloc((size_t)N_NODES * 4);
    int*   rowptr = (int*)alloc((size_t)(N_NODES + 1) * 4);
    int*   bsum   = (int*)alloc(NSCB * 4);
    int*   boff   = (int*)alloc(NSCB * 4);
    int*   gcur   = (int*)alloc(NBUCK * 4);
    float* emb    = (float*)alloc(NGRAPH * HC * 4);
    int*   se     = (int*)alloc(2 * NGRAPH * 4);

    hipMemsetAsync(params, 0, 64, stream);
    hipMemsetAsync(cnt, 0, (size_t)N_NODES * 4, stream);
    hipMemsetAsync(se, 0, 2 * NGRAPH * 4, stream);

    const int nThr = N_NODES * HC;  // 3.2M
    const int nBlk = (nThr + 255) / 256;
    const int nBlkN = (N_NODES + 255) / 256;
    const int nBlkB = (N_EDGES + EPB - 1) / EPB;

    // small precompute + CSR build (two-pass locality-aware counting sort)
    k_ea_sum<<<1024, 256, 0, stream>>>(ea, params);
    k_prep<<<1, 64, 0, stream>>>(We1, ae1, We2, ae2, params);
    k_hist<<<2048, 256, 0, stream>>>(dstp, cnt);
    k_scan1<<<NSCB, 256, 0, stream>>>(cnt, bsum);
    k_scan2<<<1, 256, 0, stream>>>(bsum, boff);
    k_scan3<<<NSCB, 256, 0, stream>>>(cnt, boff, rowptr);
    k_gcur_init<<<1, 256, 0, stream>>>(rowptr, gcur);
    k_bucket<<<nBlkB, 256, 0, stream>>>(srcp, dstp, ea, gcur, staged, sdst);
    k_scatter<<<NBUCK, 256, 0, stream>>>(staged, sdst, rowptr, epack);

    // ----- layer 1 (hbuf/obuf overwrite staged region; stream-ordered, safe) -----
    k_linear<F_IN><<<nBlk, 256, 0, stream>>>(x, W1, as1, ad1, hbuf, asrc, adst);
    k_gat<<<nBlk, 256, 0, stream>>>(rowptr, epack, hbuf, asrc, adst, params, 2, b1, 1, obuf);

    // ----- layer 2 -----
    k_linear<HC><<<nBlk, 256, 0, stream>>>(obuf, W2, as2, ad2, hbuf, asrc, adst);
    k_gat<<<nBlk, 256, 0, stream>>>(rowptr, epack, hbuf, asrc, adst, params, 4, b2, 0, obuf);

    // ----- pool + MLP -----
    k_bounds<<<nBlkN, 256, 0, stream>>>(batch, se);
    k_pool<<<NGRAPH, 256, 0, stream>>>(obuf, se, emb);
    k_mlp<<<NGRAPH, 32, 0, stream>>>(emb, Wf1, bf1, Wf2, bf2, out);
}